// Round 13
// baseline (302.337 us; speedup 1.0000x reference)
//
#include <hip/hip_runtime.h>
#include <math.h>

#define N_NODES 50000
#define N_EDGES 800000
#define NFEAT   512
#define NHID    64
#define NCLASS  40
#define SLOTS   64   // bucket capacity: deg ~ Poisson(16), P(deg>64) ~ 1e-19

#define GEMM_BLOCKS (N_NODES / 16)         // 3125 (16 rows/block, K-split x4)
#define SCAT_BLOCKS (N_EDGES / 256)        // 3125 (256 edges/block)

typedef __attribute__((ext_vector_type(8))) short bf16x8;   // 8 bf16 (4 VGPRs)
typedef __attribute__((ext_vector_type(4))) float f32x4;    // MFMA C/D

__device__ inline unsigned short f2bf(float f) {            // fp32 -> bf16 RNE
    unsigned int u = __float_as_uint(f);
    u += 0x7FFFu + ((u >> 16) & 1u);
    return (unsigned short)(u >> 16);
}
__device__ inline float bf2f(unsigned short u) {            // bf16 -> fp32
    return __uint_as_float(((unsigned int)u) << 16);
}
__device__ inline float bflo(unsigned int u) {              // low bf16 of word
    return __uint_as_float(u << 16);
}
__device__ inline float bfhi(unsigned int u) {              // high bf16 of word
    return __uint_as_float(u & 0xFFFF0000u);
}

// ---------------------------------------------------------------------------
// Round 22: K-split gemm1. R3-R6 proved 16-rows-per-wave fixes 3125 gemm
// waves (~12/CU tail) -> 1.33TB/s latency wall; R5's col-split 4x'd waves
// but also 4x'd A-load instrs (regressed). K-split: block = 16 rows, its 4
// waves own disjoint 128-wide K-chunks of the SAME rows -> 12500 waves, same
// total load instrs, all 8 A-loads per wave independent (issued upfront).
// Partials reduced via padded LDS tile + one __syncthreads. Plain HIP only
// (no asm/raw-barrier/gl_lds — R19/R20's hang class excluded).
// ---------------------------------------------------------------------------

__global__ __launch_bounds__(256) void init_kernel(int* __restrict__ cursor,
                                                   const float* __restrict__ W1,
                                                   unsigned short* __restrict__ w1t,
                                                   uint4* __restrict__ ev2q) {
    int i = blockIdx.x * blockDim.x + threadIdx.x;   // grid: 800000 threads
    if (i < N_NODES) cursor[i] = 0;
    if (i < NFEAT * NHID) {                      // W1 is [k][c], c fastest
        int k = i >> 6, c = i & 63;
        w1t[(size_t)c * NFEAT + k] = f2bf(W1[i]);
    }
    ev2q[i] = make_uint4(0u, 0u, 0u, 0u);        // exact: 800000*16B = 12.8MB
}

// ---------------------------------------------------------------------------
// Fused GEMM1 + scatter. Blocks [0,3125): xw = x @ W1 (MFMA, bf16 out, one
// 128B line per row); 16 rows/block, wave wv owns K in [wv*128, wv*128+128).
// Blocks [3125,6250): bucket-scatter edges.
// Fragment maps (HW-verified m89/m120): A[m=lane&15][k=quad*8+j],
// B[k=quad*8+j][n=lane&15], D: col=lane&15, row=quad*4+reg.
// ---------------------------------------------------------------------------
__global__ __launch_bounds__(256) void gemm1_scatter_kernel(
        const float* __restrict__ x,
        const unsigned short* __restrict__ w1t,
        unsigned short* __restrict__ xw,
        const int* __restrict__ dst,
        const int* __restrict__ src,
        const float* __restrict__ adj_vals,
        int* __restrict__ cursor,
        unsigned int* __restrict__ ev2) {
    __shared__ float red[4][16][68];             // 17.4 KB (68: bank-pad, 16B-aligned rows)
    const int tid = threadIdx.x;
    const unsigned b = blockIdx.x;

    if (b >= GEMM_BLOCKS) {                      // ---- scatter block ----
        const int i = (b - GEMM_BLOCKS) * 256 + tid;   // exact: 3125*256 = 800000
        const int d = dst[i];
        const int p = atomicAdd(&cursor[d], 1);
        if (p < SLOTS)   // insurance; statistically never taken
            ev2[(size_t)d * SLOTS + p] =
                (unsigned int)src[i] | ((unsigned int)f2bf(adj_vals[i]) << 16);
        return;
    }

    // ---- gemm block: 16 rows, wave wv = K-chunk wv (4 K-steps of 32) ----
    const int lane = tid & 63;
    const int wv   = tid >> 6;
    const int i16  = lane & 15;
    const int quad = lane >> 4;
    const int kb   = wv * 128;

    const float* xrow = x + (size_t)(b * 16 + i16) * NFEAT + kb + quad * 8;
    const unsigned short* wb = w1t + (size_t)i16 * NFEAT + kb + quad * 8;

    // A: all 8 loads independent, issued upfront (max MLP, no rotation chain)
    float4 pa[4], pb[4];
#pragma unroll
    for (int s = 0; s < 4; ++s) {
        pa[s] = *reinterpret_cast<const float4*>(xrow + s * 32);
        pb[s] = *reinterpret_cast<const float4*>(xrow + s * 32 + 4);
    }
    // B: 2-deep rotation (L1/L2-resident)
    bf16x8 bfr[2][4];
#pragma unroll
    for (int s = 0; s < 2; ++s)
#pragma unroll
        for (int ct = 0; ct < 4; ++ct)
            bfr[s][ct] = *reinterpret_cast<const bf16x8*>(
                wb + (size_t)ct * 16 * NFEAT + s * 32);

    f32x4 acc[4];
#pragma unroll
    for (int ct = 0; ct < 4; ++ct) acc[ct] = (f32x4){0.f, 0.f, 0.f, 0.f};

#pragma unroll
    for (int s = 0; s < 4; ++s) {                // fully unrolled: static idx
        float4 xa = pa[s], xb = pb[s];
        bf16x8 a;
        a[0] = (short)f2bf(xa.x); a[1] = (short)f2bf(xa.y);
        a[2] = (short)f2bf(xa.z); a[3] = (short)f2bf(xa.w);
        a[4] = (short)f2bf(xb.x); a[5] = (short)f2bf(xb.y);
        a[6] = (short)f2bf(xb.z); a[7] = (short)f2bf(xb.w);
#pragma unroll
        for (int ct = 0; ct < 4; ++ct)
            acc[ct] = __builtin_amdgcn_mfma_f32_16x16x32_bf16(a, bfr[s & 1][ct], acc[ct], 0, 0, 0);
        if (s + 2 < 4) {
#pragma unroll
            for (int ct = 0; ct < 4; ++ct)
                bfr[s & 1][ct] = *reinterpret_cast<const bf16x8*>(
                    wb + (size_t)ct * 16 * NFEAT + (s + 2) * 32);
        }
    }

    // partials -> LDS: D elem (row=quad*4+reg, col=ct*16+i16)
#pragma unroll
    for (int ct = 0; ct < 4; ++ct)
#pragma unroll
        for (int reg = 0; reg < 4; ++reg)
            red[wv][quad * 4 + reg][ct * 16 + i16] = acc[ct][reg];
    __syncthreads();

    // cross-wave reduce + coalesced bf16 store: thread t -> row t>>4, cols (t&15)*4..+3
    {
        const int r  = tid >> 4;
        const int cq = tid & 15;
        float4 s0 = *reinterpret_cast<const float4*>(&red[0][r][cq * 4]);
        float4 s1 = *reinterpret_cast<const float4*>(&red[1][r][cq * 4]);
        float4 s2 = *reinterpret_cast<const float4*>(&red[2][r][cq * 4]);
        float4 s3 = *reinterpret_cast<const float4*>(&red[3][r][cq * 4]);
        ushort4 o;
        o.x = f2bf(s0.x + s1.x + s2.x + s3.x);
        o.y = f2bf(s0.y + s1.y + s2.y + s3.y);
        o.z = f2bf(s0.z + s1.z + s2.z + s3.z);
        o.w = f2bf(s0.w + s1.w + s2.w + s3.w);
        *reinterpret_cast<ushort4*>(xw + (size_t)(b * 16 + r) * NHID + cq * 4) = o;
    }
}

// ---------------------------------------------------------------------------
// Fused SpMM1 + bias + relu + GEMM2. Wave per row; lane = (ep,f): edge-group
// ep = lane>>4 takes chunk [ep*4 + 16k, +4) via ONE uint4; f = lane&15 covers
// features 4f..4f+3. 16 gather lines in flight. shfl_xor(16,32) combines
// groups. Epilogue: all 64 lanes, 1 class each (lane>=40 -> 0), ONE coalesced
// 128B row store (also zeroes pad cols 40..63).
// ---------------------------------------------------------------------------
__global__ __launch_bounds__(256) void spmm1_gemm2_kernel(
        const unsigned short* __restrict__ xw,
        const unsigned int* __restrict__ ev2,
        const int* __restrict__ counts,
        const float* __restrict__ b1,
        const float* __restrict__ W2,
        unsigned short* __restrict__ hw) {
    __shared__ float w2lds[NHID * NCLASS];       // 10.25 KB, layout == W2
    __shared__ float hlds[4][NHID];              // 1 KB
    const int tid  = threadIdx.x;
    const int lane = tid & 63;
    const int wv   = tid >> 6;
    const int ep   = lane >> 4;                  // 0..3 edge-parallel group
    const int f    = lane & 15;                  // feature quad

    for (int idx = tid; idx < NHID * NCLASS; idx += 256) w2lds[idx] = W2[idx];
    __syncthreads();

    const int row = blockIdx.x * 4 + wv;         // exact: 12500*4 = 50000
    int cnt = counts[row];
    if (cnt > SLOTS) cnt = SLOTS;
    const unsigned int* erow = ev2 + (size_t)row * SLOTS;

    float a0 = 0.f, a1 = 0.f, a2 = 0.f, a3 = 0.f;
    for (int i0 = ep * 4; i0 < cnt; i0 += 16) {  // pad slots are exact zeros
        uint4 e4 = *reinterpret_cast<const uint4*>(erow + i0);
        uint2 g0 = *reinterpret_cast<const uint2*>(xw + (size_t)(e4.x & 0xFFFFu) * NHID + f * 4);
        uint2 g1 = *reinterpret_cast<const uint2*>(xw + (size_t)(e4.y & 0xFFFFu) * NHID + f * 4);
        uint2 g2 = *reinterpret_cast<const uint2*>(xw + (size_t)(e4.z & 0xFFFFu) * NHID + f * 4);
        uint2 g3 = *reinterpret_cast<const uint2*>(xw + (size_t)(e4.w & 0xFFFFu) * NHID + f * 4);
        float v0 = bfhi(e4.x), v1 = bfhi(e4.y), v2 = bfhi(e4.z), v3 = bfhi(e4.w);
        a0 = fmaf(v0, bflo(g0.x), a0); a1 = fmaf(v0, bfhi(g0.x), a1);
        a2 = fmaf(v0, bflo(g0.y), a2); a3 = fmaf(v0, bfhi(g0.y), a3);
        a0 = fmaf(v1, bflo(g1.x), a0); a1 = fmaf(v1, bfhi(g1.x), a1);
        a2 = fmaf(v1, bflo(g1.y), a2); a3 = fmaf(v1, bfhi(g1.y), a3);
        a0 = fmaf(v2, bflo(g2.x), a0); a1 = fmaf(v2, bfhi(g2.x), a1);
        a2 = fmaf(v2, bflo(g2.y), a2); a3 = fmaf(v2, bfhi(g2.y), a3);
        a0 = fmaf(v3, bflo(g3.x), a0); a1 = fmaf(v3, bfhi(g3.x), a1);
        a2 = fmaf(v3, bflo(g3.y), a2); a3 = fmaf(v3, bfhi(g3.y), a3);
    }
    // combine the 4 edge groups: lanes {L, L^16, L^32, L^48} share f
    a0 += __shfl_xor(a0, 16); a0 += __shfl_xor(a0, 32);
    a1 += __shfl_xor(a1, 16); a1 += __shfl_xor(a1, 32);
    a2 += __shfl_xor(a2, 16); a2 += __shfl_xor(a2, 32);
    a3 += __shfl_xor(a3, 16); a3 += __shfl_xor(a3, 32);

    if (ep == 0) {                               // h row -> LDS (fp32)
        float4 bv = *reinterpret_cast<const float4*>(b1 + f * 4);
        float4 hv;
        hv.x = fmaxf(a0 + bv.x, 0.f);
        hv.y = fmaxf(a1 + bv.y, 0.f);
        hv.z = fmaxf(a2 + bv.z, 0.f);
        hv.w = fmaxf(a3 + bv.w, 0.f);
        *reinterpret_cast<float4*>(&hlds[wv][f * 4]) = hv;
    }

    // gemm2 epilogue: all 64 lanes, 1 class each (wave-internal LDS order)
    const int c = lane < NCLASS ? lane : (NCLASS - 1);
    float d = 0.f;
#pragma unroll
    for (int k = 0; k < NHID; ++k)
        d = fmaf(hlds[wv][k], w2lds[k * NCLASS + c], d);
    hw[(size_t)row * 64 + lane] = (lane < NCLASS) ? f2bf(d) : (unsigned short)0;
}

// ---------------------------------------------------------------------------
// SpMM2 + b2 + log_softmax. Wave per row; lane = (ep,f): 4 classes per lane
// (4f..4f+3, valid f<10); chunked uint4 edge reads; 16 gather lines in
// flight. shfl_xor(16,32) combines groups; shfl_xor(1..8) softmax reduces.
// ---------------------------------------------------------------------------
__global__ void spmm2_lsm_kernel(const unsigned short* __restrict__ hw,
                                 const unsigned int* __restrict__ ev2,
                                 const int* __restrict__ counts,
                                 const float* __restrict__ b2,
                                 float* __restrict__ out) {
    const int lane = threadIdx.x & 63;
    const int row  = blockIdx.x * 4 + (threadIdx.x >> 6);
    const int ep   = lane >> 4;
    const int f    = lane & 15;
    int cnt = counts[row];
    if (cnt > SLOTS) cnt = SLOTS;
    const unsigned int* erow = ev2 + (size_t)row * SLOTS;

    float a0 = 0.f, a1 = 0.f, a2 = 0.f, a3 = 0.f;
    for (int i0 = ep * 4; i0 < cnt; i0 += 16) {  // pad slots are exact zeros
        uint4 e4 = *reinterpret_cast<const uint4*>(erow + i0);
        uint2 g0 = *reinterpret_cast<const uint2*>(hw + (size_t)(e4.x & 0xFFFFu) * 64 + f * 4);
        uint2 g1 = *reinterpret_cast<const uint2*>(hw + (size_t)(e4.y & 0xFFFFu) * 64 + f * 4);
        uint2 g2 = *reinterpret_cast<const uint2*>(hw + (size_t)(e4.z & 0xFFFFu) * 64 + f * 4);
        uint2 g3 = *reinterpret_cast<const uint2*>(hw + (size_t)(e4.w & 0xFFFFu) * 64 + f * 4);
        float v0 = bfhi(e4.x), v1 = bfhi(e4.y), v2 = bfhi(e4.z), v3 = bfhi(e4.w);
        a0 = fmaf(v0, bflo(g0.x), a0); a1 = fmaf(v0, bfhi(g0.x), a1);
        a2 = fmaf(v0, bflo(g0.y), a2); a3 = fmaf(v0, bfhi(g0.y), a3);
        a0 = fmaf(v1, bflo(g1.x), a0); a1 = fmaf(v1, bfhi(g1.x), a1);
        a2 = fmaf(v1, bflo(g1.y), a2); a3 = fmaf(v1, bfhi(g1.y), a3);
        a0 = fmaf(v2, bflo(g2.x), a0); a1 = fmaf(v2, bfhi(g2.x), a1);
        a2 = fmaf(v2, bflo(g2.y), a2); a3 = fmaf(v2, bfhi(g2.y), a3);
        a0 = fmaf(v3, bflo(g3.x), a0); a1 = fmaf(v3, bfhi(g3.x), a1);
        a2 = fmaf(v3, bflo(g3.y), a2); a3 = fmaf(v3, bfhi(g3.y), a3);
    }
    a0 += __shfl_xor(a0, 16); a0 += __shfl_xor(a0, 32);
    a1 += __shfl_xor(a1, 16); a1 += __shfl_xor(a1, 32);
    a2 += __shfl_xor(a2, 16); a2 += __shfl_xor(a2, 32);
    a3 += __shfl_xor(a3, 16); a3 += __shfl_xor(a3, 32);

    const bool active = f < 10;                  // classes 4f..4f+3
    const int  fb     = active ? f : 9;
    float4 bv = *reinterpret_cast<const float4*>(b2 + fb * 4);
    float l0 = a0 + bv.x, l1 = a1 + bv.y, l2 = a2 + bv.z, l3 = a3 + bv.w;

    float m = active ? fmaxf(fmaxf(l0, l1), fmaxf(l2, l3)) : -INFINITY;
#pragma unroll
    for (int o = 8; o > 0; o >>= 1) m = fmaxf(m, __shfl_xor(m, o));
    float s = active ? (expf(l0 - m) + expf(l1 - m) + expf(l2 - m) + expf(l3 - m)) : 0.f;
#pragma unroll
    for (int o = 8; o > 0; o >>= 1) s += __shfl_xor(s, o);
    const float lse = m + logf(s);

    if (active && ep == 0) {
        float4 o4;
        o4.x = l0 - lse; o4.y = l1 - lse; o4.z = l2 - lse; o4.w = l3 - lse;
        *reinterpret_cast<float4*>(&out[(size_t)row * NCLASS + f * 4]) = o4;
    }
}

// ---------------------------------------------------------------------------

extern "C" void kernel_launch(void* const* d_in, const int* in_sizes, int n_in,
                              void* d_out, int out_size, void* d_ws, size_t ws_size,
                              hipStream_t stream) {
    const float* x        = (const float*)d_in[0];
    const float* adj_vals = (const float*)d_in[1];
    const float* W1       = (const float*)d_in[2];
    const float* b1       = (const float*)d_in[3];
    const float* W2       = (const float*)d_in[4];
    const float* b2       = (const float*)d_in[5];
    const int*   src      = (const int*)d_in[6];
    const int*   dst      = (const int*)d_in[7];
    float* out = (float*)d_out;

    // Workspace layout (25.8 MB). w1t aliases hw's region: w1t is dead after
    // gemm1_scatter completes, hw written by the following kernel. ev2 is
    // 16B-aligned (13,000,000 % 16 == 0) for the uint4 zero-fill.
    const size_t OFF_HW   = 6400000;             // hw  : 50000*64 bf16 (6.4 MB)
    const size_t OFF_CUR  = 12800000;            // cursor/counts : 50000 int
    const size_t OFF_EV   = 13000000;            // ev2 : 50000*64 uint (12.8 MB)
    const size_t REQUIRED = OFF_EV + (size_t)N_NODES * SLOTS * 4;  // 25,800,000 B
    if (ws_size < REQUIRED) return;              // refuse to write OOB

    char* ws = (char*)d_ws;
    unsigned short* xw     = (unsigned short*)(ws);
    unsigned short* hw     = (unsigned short*)(ws + OFF_HW);
    unsigned short* w1t    = (unsigned short*)(ws + OFF_HW);  // dead before hw written
    int*            cursor = (int*)  (ws + OFF_CUR);
    unsigned int*   ev2    = (unsigned int*)(ws + OFF_EV);

    init_kernel<<<3125, 256, 0, stream>>>(cursor, W1, w1t, (uint4*)ev2);
    gemm1_scatter_kernel<<<GEMM_BLOCKS + SCAT_BLOCKS, 256, 0, stream>>>(
        x, w1t, xw, dst, src, adj_vals, cursor, ev2);
    spmm1_gemm2_kernel<<<N_NODES / 4, 256, 0, stream>>>(xw, ev2, cursor, b1, W2, hw);
    spmm2_lsm_kernel<<<N_NODES / 4, 256, 0, stream>>>(hw, ev2, cursor, b2, out);
}

// Round 14
// 266.561 us; speedup vs baseline: 1.1342x; 1.1342x over previous
//
#include <hip/hip_runtime.h>
#include <math.h>

#define N_NODES 50000
#define N_EDGES 800000
#define NFEAT   512
#define NHID    64
#define NCLASS  40
#define SLOTS   64   // bucket capacity: deg ~ Poisson(16), P(deg>64) ~ 1e-19

#define GEMM_BLOCKS ((N_NODES + 63) / 64)  // 782  (4 waves x 16 rows)
#define SCAT_BLOCKS (N_EDGES / 256)        // 3125 (256 edges/block)

typedef __attribute__((ext_vector_type(8))) short bf16x8;   // 8 bf16 (4 VGPRs)
typedef __attribute__((ext_vector_type(4))) float f32x4;    // MFMA C/D

__device__ inline unsigned short f2bf(float f) {            // fp32 -> bf16 RNE
    unsigned int u = __float_as_uint(f);
    u += 0x7FFFu + ((u >> 16) & 1u);
    return (unsigned short)(u >> 16);
}
__device__ inline float bf2f(unsigned short u) {            // bf16 -> fp32
    return __uint_as_float(((unsigned int)u) << 16);
}
__device__ inline float bflo(unsigned int u) {              // low bf16 of word
    return __uint_as_float(u << 16);
}
__device__ inline float bfhi(unsigned int u) {              // high bf16 of word
    return __uint_as_float(u & 0xFFFF0000u);
}

// ---------------------------------------------------------------------------
// Round 23: revert R13's K-split (110us: LDS-reduce bank conflicts + block
// churn). Base = R12 (280.1, best). Two low-risk untried tweaks only:
// (1) gemm A-prefetch depth 4->6 (12 loads in flight, VGPR ~116 < 128 cliff);
// (2) spmm1g2 stages W2 via registers BEFORE the gather loop, LDS-write +
// syncthreads AFTER it (T14: W2 latency hides under gathers).
// ---------------------------------------------------------------------------

__global__ __launch_bounds__(256) void init_kernel(int* __restrict__ cursor,
                                                   const float* __restrict__ W1,
                                                   unsigned short* __restrict__ w1t,
                                                   uint4* __restrict__ ev2q) {
    int i = blockIdx.x * blockDim.x + threadIdx.x;   // grid: 800000 threads
    if (i < N_NODES) cursor[i] = 0;
    if (i < NFEAT * NHID) {                      // W1 is [k][c], c fastest
        int k = i >> 6, c = i & 63;
        w1t[(size_t)c * NFEAT + k] = f2bf(W1[i]);
    }
    ev2q[i] = make_uint4(0u, 0u, 0u, 0u);        // exact: 800000*16B = 12.8MB
}

// ---------------------------------------------------------------------------
// Fused GEMM1 + scatter (R4/R12 proven form, depth-6 A rotation).
// Blocks [0,782): xw = x @ W1 (MFMA, bf16 out, one 128B line per row),
// 4 waves x 16 rows. Blocks [782,782+3125): bucket-scatter edges.
// Fragment maps (HW-verified m89/m120): A[m=lane&15][k=quad*8+j],
// B[k=quad*8+j][n=lane&15], D: col=lane&15, row=quad*4+reg.
// ---------------------------------------------------------------------------
__global__ __launch_bounds__(256) void gemm1_scatter_kernel(
        const float* __restrict__ x,
        const unsigned short* __restrict__ w1t,
        unsigned short* __restrict__ xw,
        const int* __restrict__ dst,
        const int* __restrict__ src,
        const float* __restrict__ adj_vals,
        int* __restrict__ cursor,
        unsigned int* __restrict__ ev2) {
    const int tid = threadIdx.x;
    const unsigned b = blockIdx.x;

    if (b >= GEMM_BLOCKS) {                      // ---- scatter block ----
        const int i = (b - GEMM_BLOCKS) * 256 + tid;   // exact: 3125*256 = 800000
        const int d = dst[i];
        const int p = atomicAdd(&cursor[d], 1);
        if (p < SLOTS)   // insurance; statistically never taken
            ev2[(size_t)d * SLOTS + p] =
                (unsigned int)src[i] | ((unsigned int)f2bf(adj_vals[i]) << 16);
        return;
    }

    // ---- gemm block: 4 waves x 16 rows, K=512 in 16 steps of 32 ----
    const int lane = tid & 63;
    const int wv   = tid >> 6;
    const int i16  = lane & 15;
    const int quad = lane >> 4;

    const int arow = b * 64 + wv * 16 + i16;
    const int arc  = arow < N_NODES ? arow : N_NODES - 1;
    const float* xrow = x + (size_t)arc * NFEAT + quad * 8;
    const unsigned short* wb = w1t + (size_t)i16 * NFEAT + quad * 8;

    f32x4 acc0 = {0.f, 0.f, 0.f, 0.f};
    f32x4 acc1 = acc0, acc2 = acc0, acc3 = acc0;

    float4 pa[6], pb[6];      // A prefetch, 6 K-steps deep (12 loads in flight)
    bf16x8 bf0[2], bf1[2], bf2[2], bf3[2];   // B prefetch, 2 deep (L1/L2-resident)

#pragma unroll
    for (int s = 0; s < 6; ++s) {
        pa[s] = *reinterpret_cast<const float4*>(xrow + s * 32);
        pb[s] = *reinterpret_cast<const float4*>(xrow + s * 32 + 4);
    }
#pragma unroll
    for (int s = 0; s < 2; ++s) {
        bf0[s] = *reinterpret_cast<const bf16x8*>(wb + 0 * 16 * NFEAT + s * 32);
        bf1[s] = *reinterpret_cast<const bf16x8*>(wb + 1 * 16 * NFEAT + s * 32);
        bf2[s] = *reinterpret_cast<const bf16x8*>(wb + 2 * 16 * NFEAT + s * 32);
        bf3[s] = *reinterpret_cast<const bf16x8*>(wb + 3 * 16 * NFEAT + s * 32);
    }

#pragma unroll
    for (int s = 0; s < 16; ++s) {               // fully unrolled: static idx
        float4 xa = pa[s % 6], xb = pb[s % 6];
        bf16x8 a;
        a[0] = (short)f2bf(xa.x); a[1] = (short)f2bf(xa.y);
        a[2] = (short)f2bf(xa.z); a[3] = (short)f2bf(xa.w);
        a[4] = (short)f2bf(xb.x); a[5] = (short)f2bf(xb.y);
        a[6] = (short)f2bf(xb.z); a[7] = (short)f2bf(xb.w);
        acc0 = __builtin_amdgcn_mfma_f32_16x16x32_bf16(a, bf0[s & 1], acc0, 0, 0, 0);
        acc1 = __builtin_amdgcn_mfma_f32_16x16x32_bf16(a, bf1[s & 1], acc1, 0, 0, 0);
        acc2 = __builtin_amdgcn_mfma_f32_16x16x32_bf16(a, bf2[s & 1], acc2, 0, 0, 0);
        acc3 = __builtin_amdgcn_mfma_f32_16x16x32_bf16(a, bf3[s & 1], acc3, 0, 0, 0);
        if (s + 6 < 16) {
            pa[s % 6] = *reinterpret_cast<const float4*>(xrow + (s + 6) * 32);
            pb[s % 6] = *reinterpret_cast<const float4*>(xrow + (s + 6) * 32 + 4);
        }
        if (s + 2 < 16) {
            bf0[s & 1] = *reinterpret_cast<const bf16x8*>(wb + 0 * 16 * NFEAT + (s + 2) * 32);
            bf1[s & 1] = *reinterpret_cast<const bf16x8*>(wb + 1 * 16 * NFEAT + (s + 2) * 32);
            bf2[s & 1] = *reinterpret_cast<const bf16x8*>(wb + 2 * 16 * NFEAT + (s + 2) * 32);
            bf3[s & 1] = *reinterpret_cast<const bf16x8*>(wb + 3 * 16 * NFEAT + (s + 2) * 32);
        }
    }

    const int orow0 = b * 64 + wv * 16 + quad * 4;
#pragma unroll
    for (int reg = 0; reg < 4; ++reg) {
        const int orow = orow0 + reg;
        if (orow < N_NODES) {
            unsigned short* op = xw + (size_t)orow * NHID + i16;
            op[ 0] = f2bf(acc0[reg]);
            op[16] = f2bf(acc1[reg]);
            op[32] = f2bf(acc2[reg]);
            op[48] = f2bf(acc3[reg]);
        }
    }
}

// ---------------------------------------------------------------------------
// Fused SpMM1 + bias + relu + GEMM2. Wave per row; lane = (ep,f): edge-group
// ep = lane>>4 takes chunk [ep*4 + 16k, +4) via ONE uint4; f = lane&15 covers
// features 4f..4f+3. 16 gather lines in flight. shfl_xor(16,32) combines
// groups. W2 is REGISTER-staged before the gather loop and LDS-committed
// after it (T14: load latency hides under gathers). Epilogue: all 64 lanes,
// 1 class each, ONE coalesced 128B row store (zeroes pad cols 40..63).
// ---------------------------------------------------------------------------
__global__ __launch_bounds__(256) void spmm1_gemm2_kernel(
        const unsigned short* __restrict__ xw,
        const unsigned int* __restrict__ ev2,
        const int* __restrict__ counts,
        const float* __restrict__ b1,
        const float* __restrict__ W2,
        unsigned short* __restrict__ hw) {
    __shared__ float w2lds[NHID * NCLASS];       // 10.25 KB, layout == W2
    __shared__ float hlds[4][NHID];              // 1 KB
    const int tid  = threadIdx.x;
    const int lane = tid & 63;
    const int wv   = tid >> 6;
    const int ep   = lane >> 4;                  // 0..3 edge-parallel group
    const int f    = lane & 15;                  // feature quad

    // stage W2 into registers (loads issue now, land during gather loop)
    float w2r[10];
#pragma unroll
    for (int j = 0; j < 10; ++j) w2r[j] = W2[tid + j * 256];

    const int row = blockIdx.x * 4 + wv;         // exact: 12500*4 = 50000
    int cnt = counts[row];
    if (cnt > SLOTS) cnt = SLOTS;
    const unsigned int* erow = ev2 + (size_t)row * SLOTS;

    float a0 = 0.f, a1 = 0.f, a2 = 0.f, a3 = 0.f;
    for (int i0 = ep * 4; i0 < cnt; i0 += 16) {  // pad slots are exact zeros
        uint4 e4 = *reinterpret_cast<const uint4*>(erow + i0);
        uint2 g0 = *reinterpret_cast<const uint2*>(xw + (size_t)(e4.x & 0xFFFFu) * NHID + f * 4);
        uint2 g1 = *reinterpret_cast<const uint2*>(xw + (size_t)(e4.y & 0xFFFFu) * NHID + f * 4);
        uint2 g2 = *reinterpret_cast<const uint2*>(xw + (size_t)(e4.z & 0xFFFFu) * NHID + f * 4);
        uint2 g3 = *reinterpret_cast<const uint2*>(xw + (size_t)(e4.w & 0xFFFFu) * NHID + f * 4);
        float v0 = bfhi(e4.x), v1 = bfhi(e4.y), v2 = bfhi(e4.z), v3 = bfhi(e4.w);
        a0 = fmaf(v0, bflo(g0.x), a0); a1 = fmaf(v0, bfhi(g0.x), a1);
        a2 = fmaf(v0, bflo(g0.y), a2); a3 = fmaf(v0, bfhi(g0.y), a3);
        a0 = fmaf(v1, bflo(g1.x), a0); a1 = fmaf(v1, bfhi(g1.x), a1);
        a2 = fmaf(v1, bflo(g1.y), a2); a3 = fmaf(v1, bfhi(g1.y), a3);
        a0 = fmaf(v2, bflo(g2.x), a0); a1 = fmaf(v2, bfhi(g2.x), a1);
        a2 = fmaf(v2, bflo(g2.y), a2); a3 = fmaf(v2, bfhi(g2.y), a3);
        a0 = fmaf(v3, bflo(g3.x), a0); a1 = fmaf(v3, bfhi(g3.x), a1);
        a2 = fmaf(v3, bflo(g3.y), a2); a3 = fmaf(v3, bfhi(g3.y), a3);
    }
    // combine the 4 edge groups: lanes {L, L^16, L^32, L^48} share f
    a0 += __shfl_xor(a0, 16); a0 += __shfl_xor(a0, 32);
    a1 += __shfl_xor(a1, 16); a1 += __shfl_xor(a1, 32);
    a2 += __shfl_xor(a2, 16); a2 += __shfl_xor(a2, 32);
    a3 += __shfl_xor(a3, 16); a3 += __shfl_xor(a3, 32);

    if (ep == 0) {                               // h row -> LDS (fp32)
        float4 bv = *reinterpret_cast<const float4*>(b1 + f * 4);
        float4 hv;
        hv.x = fmaxf(a0 + bv.x, 0.f);
        hv.y = fmaxf(a1 + bv.y, 0.f);
        hv.z = fmaxf(a2 + bv.z, 0.f);
        hv.w = fmaxf(a3 + bv.w, 0.f);
        *reinterpret_cast<float4*>(&hlds[wv][f * 4]) = hv;
    }

    // commit W2 registers to LDS; barrier covers both w2lds and nothing else
#pragma unroll
    for (int j = 0; j < 10; ++j) w2lds[tid + j * 256] = w2r[j];
    __syncthreads();

    // gemm2 epilogue: all 64 lanes, 1 class each (wave-internal LDS order for hlds)
    const int c = lane < NCLASS ? lane : (NCLASS - 1);
    float d = 0.f;
#pragma unroll
    for (int k = 0; k < NHID; ++k)
        d = fmaf(hlds[wv][k], w2lds[k * NCLASS + c], d);
    hw[(size_t)row * 64 + lane] = (lane < NCLASS) ? f2bf(d) : (unsigned short)0;
}

// ---------------------------------------------------------------------------
// SpMM2 + b2 + log_softmax. Wave per row; lane = (ep,f): 4 classes per lane
// (4f..4f+3, valid f<10); chunked uint4 edge reads; 16 gather lines in
// flight. shfl_xor(16,32) combines groups; shfl_xor(1..8) softmax reduces.
// ---------------------------------------------------------------------------
__global__ void spmm2_lsm_kernel(const unsigned short* __restrict__ hw,
                                 const unsigned int* __restrict__ ev2,
                                 const int* __restrict__ counts,
                                 const float* __restrict__ b2,
                                 float* __restrict__ out) {
    const int lane = threadIdx.x & 63;
    const int row  = blockIdx.x * 4 + (threadIdx.x >> 6);
    const int ep   = lane >> 4;
    const int f    = lane & 15;
    int cnt = counts[row];
    if (cnt > SLOTS) cnt = SLOTS;
    const unsigned int* erow = ev2 + (size_t)row * SLOTS;

    float a0 = 0.f, a1 = 0.f, a2 = 0.f, a3 = 0.f;
    for (int i0 = ep * 4; i0 < cnt; i0 += 16) {  // pad slots are exact zeros
        uint4 e4 = *reinterpret_cast<const uint4*>(erow + i0);
        uint2 g0 = *reinterpret_cast<const uint2*>(hw + (size_t)(e4.x & 0xFFFFu) * 64 + f * 4);
        uint2 g1 = *reinterpret_cast<const uint2*>(hw + (size_t)(e4.y & 0xFFFFu) * 64 + f * 4);
        uint2 g2 = *reinterpret_cast<const uint2*>(hw + (size_t)(e4.z & 0xFFFFu) * 64 + f * 4);
        uint2 g3 = *reinterpret_cast<const uint2*>(hw + (size_t)(e4.w & 0xFFFFu) * 64 + f * 4);
        float v0 = bfhi(e4.x), v1 = bfhi(e4.y), v2 = bfhi(e4.z), v3 = bfhi(e4.w);
        a0 = fmaf(v0, bflo(g0.x), a0); a1 = fmaf(v0, bfhi(g0.x), a1);
        a2 = fmaf(v0, bflo(g0.y), a2); a3 = fmaf(v0, bfhi(g0.y), a3);
        a0 = fmaf(v1, bflo(g1.x), a0); a1 = fmaf(v1, bfhi(g1.x), a1);
        a2 = fmaf(v1, bflo(g1.y), a2); a3 = fmaf(v1, bfhi(g1.y), a3);
        a0 = fmaf(v2, bflo(g2.x), a0); a1 = fmaf(v2, bfhi(g2.x), a1);
        a2 = fmaf(v2, bflo(g2.y), a2); a3 = fmaf(v2, bfhi(g2.y), a3);
        a0 = fmaf(v3, bflo(g3.x), a0); a1 = fmaf(v3, bfhi(g3.x), a1);
        a2 = fmaf(v3, bflo(g3.y), a2); a3 = fmaf(v3, bfhi(g3.y), a3);
    }
    a0 += __shfl_xor(a0, 16); a0 += __shfl_xor(a0, 32);
    a1 += __shfl_xor(a1, 16); a1 += __shfl_xor(a1, 32);
    a2 += __shfl_xor(a2, 16); a2 += __shfl_xor(a2, 32);
    a3 += __shfl_xor(a3, 16); a3 += __shfl_xor(a3, 32);

    const bool active = f < 10;                  // classes 4f..4f+3
    const int  fb     = active ? f : 9;
    float4 bv = *reinterpret_cast<const float4*>(b2 + fb * 4);
    float l0 = a0 + bv.x, l1 = a1 + bv.y, l2 = a2 + bv.z, l3 = a3 + bv.w;

    float m = active ? fmaxf(fmaxf(l0, l1), fmaxf(l2, l3)) : -INFINITY;
#pragma unroll
    for (int o = 8; o > 0; o >>= 1) m = fmaxf(m, __shfl_xor(m, o));
    float s = active ? (expf(l0 - m) + expf(l1 - m) + expf(l2 - m) + expf(l3 - m)) : 0.f;
#pragma unroll
    for (int o = 8; o > 0; o >>= 1) s += __shfl_xor(s, o);
    const float lse = m + logf(s);

    if (active && ep == 0) {
        float4 o4;
        o4.x = l0 - lse; o4.y = l1 - lse; o4.z = l2 - lse; o4.w = l3 - lse;
        *reinterpret_cast<float4*>(&out[(size_t)row * NCLASS + f * 4]) = o4;
    }
}

// ---------------------------------------------------------------------------

extern "C" void kernel_launch(void* const* d_in, const int* in_sizes, int n_in,
                              void* d_out, int out_size, void* d_ws, size_t ws_size,
                              hipStream_t stream) {
    const float* x        = (const float*)d_in[0];
    const float* adj_vals = (const float*)d_in[1];
    const float* W1       = (const float*)d_in[2];
    const float* b1       = (const float*)d_in[3];
    const float* W2       = (const float*)d_in[4];
    const float* b2       = (const float*)d_in[5];
    const int*   src      = (const int*)d_in[6];
    const int*   dst      = (const int*)d_in[7];
    float* out = (float*)d_out;

    // Workspace layout (25.8 MB). w1t aliases hw's region: w1t is dead after
    // gemm1_scatter completes, hw written by the following kernel. ev2 is
    // 16B-aligned (13,000,000 % 16 == 0) for the uint4 zero-fill.
    const size_t OFF_HW   = 6400000;             // hw  : 50000*64 bf16 (6.4 MB)
    const size_t OFF_CUR  = 12800000;            // cursor/counts : 50000 int
    const size_t OFF_EV   = 13000000;            // ev2 : 50000*64 uint (12.8 MB)
    const size_t REQUIRED = OFF_EV + (size_t)N_NODES * SLOTS * 4;  // 25,800,000 B
    if (ws_size < REQUIRED) return;              // refuse to write OOB

    char* ws = (char*)d_ws;
    unsigned short* xw     = (unsigned short*)(ws);
    unsigned short* hw     = (unsigned short*)(ws + OFF_HW);
    unsigned short* w1t    = (unsigned short*)(ws + OFF_HW);  // dead before hw written
    int*            cursor = (int*)  (ws + OFF_CUR);
    unsigned int*   ev2    = (unsigned int*)(ws + OFF_EV);

    init_kernel<<<3125, 256, 0, stream>>>(cursor, W1, w1t, (uint4*)ev2);
    gemm1_scatter_kernel<<<GEMM_BLOCKS + SCAT_BLOCKS, 256, 0, stream>>>(
        x, w1t, xw, dst, src, adj_vals, cursor, ev2);
    spmm1_gemm2_kernel<<<N_NODES / 4, 256, 0, stream>>>(xw, ev2, cursor, b1, W2, hw);
    spmm2_lsm_kernel<<<N_NODES / 4, 256, 0, stream>>>(hw, ev2, cursor, b2, out);
}